// Round 2
// baseline (150.852 us; speedup 1.0000x reference)
//
#include <hip/hip_runtime.h>

#define BB 4
#define NN 512
#define EE 256
#define HH 8
#define DD 32
#define SCALING 0.17677669529663687f  // 32^-0.5
#define PR 4   // rows per proj block
#define RR 8   // rows per attn block

// ---------------------------------------------------------------------------
// Fused projection: Q (pre-scaled), Kt (transposed [b,h,d,n]), and V folded
// against Wf1/2/3 -> vw[((b*H+h)*3+c)*N + m].  One staging of query serves
// all three matmuls; 512 blocks for 2 blocks/CU.
// ---------------------------------------------------------------------------
__global__ __launch_bounds__(256) void proj_kernel(
    const float* __restrict__ query,
    const float* __restrict__ Wq, const float* __restrict__ bq,
    const float* __restrict__ Wk, const float* __restrict__ bk,
    const float* __restrict__ Wv, const float* __restrict__ bv,
    const float* __restrict__ Wf1, const float* __restrict__ Wf2,
    const float* __restrict__ Wf3,
    float* __restrict__ Q, float* __restrict__ Kt, float* __restrict__ vw)
{
    __shared__ alignas(16) float s[PR][EE];    // 4 KB
    __shared__ alignas(16) float sv[PR][EE];   // 4 KB
    const int row0 = blockIdx.x * PR;
    const int tid = threadIdx.x;               // output column e

    ((float4*)s)[tid] = ((const float4*)(query + row0 * EE))[tid];
    __syncthreads();

    float aq[PR], ak[PR], av[PR];
    #pragma unroll
    for (int r = 0; r < PR; ++r) { aq[r] = 0.f; ak[r] = 0.f; av[r] = 0.f; }

    const float4* Wq4 = (const float4*)(Wq + tid * EE);
    const float4* Wk4 = (const float4*)(Wk + tid * EE);
    const float4* Wv4 = (const float4*)(Wv + tid * EE);
    for (int j4 = 0; j4 < EE / 4; ++j4) {
        const float4 wq = Wq4[j4];
        const float4 wk = Wk4[j4];
        const float4 wv_ = Wv4[j4];
        #pragma unroll
        for (int r = 0; r < PR; ++r) {
            const float4 x = *(const float4*)&s[r][j4 * 4];
            aq[r] += x.x * wq.x + x.y * wq.y + x.z * wq.z + x.w * wq.w;
            ak[r] += x.x * wk.x + x.y * wk.y + x.z * wk.z + x.w * wk.w;
            av[r] += x.x * wv_.x + x.y * wv_.y + x.z * wv_.z + x.w * wv_.w;
        }
    }

    const float bqv = bq[tid];
    const float bkv = bk[tid];
    const float bvv = bv[tid];
    const int h = tid >> 5, d = tid & 31;
    #pragma unroll
    for (int r = 0; r < PR; ++r) {
        const int grow = row0 + r;
        const int b = grow >> 9, n = grow & 511;
        Q[grow * EE + tid] = (aq[r] + bqv) * SCALING;
        Kt[((b * HH + h) * DD + d) * NN + n] = ak[r] + bkv;
        sv[r][tid] = av[r] + bvv;
    }
    __syncthreads();

    if (tid < PR * 24) {                       // 96 threads: (r, h, c)
        const int r = tid / 24;
        const int rem = tid % 24;
        const int hh = rem / 3;
        const int c = rem % 3;
        const float* Wf = (c == 0) ? Wf1 : ((c == 1) ? Wf2 : Wf3);
        float a = 0.f;
        #pragma unroll
        for (int dd = 0; dd < DD; ++dd)
            a += sv[r][hh * DD + dd] * Wf[hh * DD + dd];
        const int grow = row0 + r;
        const int b = grow >> 9, m = grow & 511;
        vw[((b * HH + hh) * 3 + c) * NN + m] = a;
    }
}

// ---------------------------------------------------------------------------
// Attention: 8 rows per block, thread tid = column m.  K column kept in 32
// registers per head, reused across all 8 rows.  No max-subtraction (logits
// bounded ~|10| << 88).  One barrier per head, LDS reduce buffer indexed by h.
// ---------------------------------------------------------------------------
__global__ __launch_bounds__(512) void attn_main_kernel(
    const float* __restrict__ Q, const float* __restrict__ Kt,
    const float* __restrict__ attn_bias, const float* __restrict__ vw,
    const float* __restrict__ delta_pos,
    const int* __restrict__ drop_edge_mask, const int* __restrict__ drop_or_add,
    const float* __restrict__ bf1, const float* __restrict__ bf2,
    const float* __restrict__ bf3,
    float* __restrict__ out)
{
    const int blk = blockIdx.x;                // 256 blocks
    const int b = blk >> 6;
    const int n0 = (blk & 63) * RR;
    const int tid = threadIdx.x;               // m
    const int wv_id = tid >> 6, ln = tid & 63;

    __shared__ alignas(16) float qs[RR][EE];       // 8 KB
    __shared__ alignas(16) float red[HH][RR][8];   // 2 KB
    __shared__ alignas(16) float r3[RR][3][8];

    ((float4*)qs)[tid] = ((const float4*)(Q + (b * NN + n0) * EE))[tid];
    __syncthreads();

    float acc0[RR], acc1[RR], acc2[RR];
    #pragma unroll
    for (int r = 0; r < RR; ++r) { acc0[r] = 0.f; acc1[r] = 0.f; acc2[r] = 0.f; }

    for (int h = 0; h < HH; ++h) {
        float kreg[DD];
        const float* kp = Kt + (b * HH + h) * DD * NN + tid;
        #pragma unroll
        for (int d = 0; d < DD; ++d) kreg[d] = kp[d * NN];

        float p[RR];
        #pragma unroll
        for (int r = 0; r < RR; ++r) {
            float l = attn_bias[((size_t)(b * HH + h) * NN + (n0 + r)) * NN + tid];
            #pragma unroll
            for (int d = 0; d < DD; ++d)
                l += qs[r][h * DD + d] * kreg[d];
            p[r] = __expf(l);
        }

        #pragma unroll
        for (int r = 0; r < RR; ++r) {
            float v = p[r];
            #pragma unroll
            for (int off = 32; off; off >>= 1)
                v += __shfl_xor(v, off, 64);
            if (ln == 0) red[h][r][wv_id] = v;
        }
        __syncthreads();

        const float* vwp = vw + (b * HH + h) * 3 * NN + tid;
        const float vw0 = vwp[0], vw1 = vwp[NN], vw2 = vwp[2 * NN];
        #pragma unroll
        for (int r = 0; r < RR; ++r) {
            const float4 s0 = *(const float4*)&red[h][r][0];
            const float4 s1 = *(const float4*)&red[h][r][4];
            const float sum = (s0.x + s0.y + s0.z + s0.w) +
                              (s1.x + s1.y + s1.z + s1.w);
            const float pi = p[r] / sum;
            acc0[r] += pi * vw0;
            acc1[r] += pi * vw1;
            acc2[r] += pi * vw2;
        }
        // no second barrier: red is indexed by h, next head writes new slots
    }

    const int doa = drop_or_add[0];
    #pragma unroll
    for (int r = 0; r < RR; ++r) {
        const float mk =
            (doa != 0 && drop_edge_mask[(n0 + r) * NN + tid] != 0) ? 0.f : 1.f;
        const float* dp = delta_pos + ((size_t)(b * NN + (n0 + r)) * NN + tid) * 3;
        float v0 = acc0[r] * dp[0] * mk;
        float v1 = acc1[r] * dp[1] * mk;
        float v2 = acc2[r] * dp[2] * mk;
        #pragma unroll
        for (int off = 32; off; off >>= 1) {
            v0 += __shfl_xor(v0, off, 64);
            v1 += __shfl_xor(v1, off, 64);
            v2 += __shfl_xor(v2, off, 64);
        }
        if (ln == 0) {
            r3[r][0][wv_id] = v0;
            r3[r][1][wv_id] = v1;
            r3[r][2][wv_id] = v2;
        }
    }
    __syncthreads();

    if (tid < RR * 3) {                        // 24 threads
        const int r = tid / 3, c = tid % 3;
        float s = 0.f;
        #pragma unroll
        for (int w = 0; w < 8; ++w) s += r3[r][c][w];
        const float bias = (c == 0) ? bf1[0] : ((c == 1) ? bf2[0] : bf3[0]);
        out[(b * NN + n0 + r) * 3 + c] = s + bias;
    }
}

// ---------------------------------------------------------------------------
extern "C" void kernel_launch(void* const* d_in, const int* in_sizes, int n_in,
                              void* d_out, int out_size, void* d_ws, size_t ws_size,
                              hipStream_t stream)
{
    const float* query          = (const float*)d_in[0];
    const float* attn_bias      = (const float*)d_in[1];
    const float* delta_pos      = (const float*)d_in[2];
    const int*   drop_edge_mask = (const int*)d_in[3];
    const float* Wq  = (const float*)d_in[4];
    const float* bq  = (const float*)d_in[5];
    const float* Wk  = (const float*)d_in[6];
    const float* bk  = (const float*)d_in[7];
    const float* Wv  = (const float*)d_in[8];
    const float* bv  = (const float*)d_in[9];
    const float* Wf1 = (const float*)d_in[10];
    const float* bf1 = (const float*)d_in[11];
    const float* Wf2 = (const float*)d_in[12];
    const float* bf2 = (const float*)d_in[13];
    const float* Wf3 = (const float*)d_in[14];
    const float* bf3 = (const float*)d_in[15];
    const int*   drop_or_add = (const int*)d_in[16];

    float* ws = (float*)d_ws;
    float* Q   = ws;                 // B*N*E   = 524288 floats
    float* Kt  = ws + 524288;        // B*H*D*N = 524288 floats
    float* vw  = ws + 1048576;       // B*H*3*N = 49152 floats

    proj_kernel<<<BB * NN / PR, 256, 0, stream>>>(query, Wq, bq, Wk, bk, Wv, bv,
                                                  Wf1, Wf2, Wf3, Q, Kt, vw);
    attn_main_kernel<<<BB * NN / RR, 512, 0, stream>>>(Q, Kt, attn_bias, vw,
                                                       delta_pos, drop_edge_mask,
                                                       drop_or_add, bf1, bf2, bf3,
                                                       (float*)d_out);
}